// Round 7
// baseline (212.824 us; speedup 1.0000x reference)
//
#include <hip/hip_runtime.h>
#include <hip/hip_bf16.h>

// DisenHAN fused, MFMA split-bf16 edition, v4 (gfx950).
// v4: single kernel again. Rounds 5/6 showed the separate pack_weights graph
// node costs ~40us of bench wall time (bench-dispatch gap 43us -> 82-86us).
// Weight fragments are now packed cooperatively per block into a 16KB LDS
// region ALIASED onto sN (unused until the main loop): 256 threads split one
// 64x64 matrix into hi/lo bf16 B-fragments (~128 VALU + 16 loads/thread),
// then each wave reads its fragments as 16 coalesced ds_read_b128.
// W1c pack -> barrier -> frag read -> barrier -> pre-encode MFMA overlapped
// with W1n pack -> barrier -> frag read -> barrier -> main loop -> barrier
// -> layer-0 (wave 0, W0n via direct strided load).
// 3-pass split-bf16 MFMA: A_hi*W_hi + A_lo*W_hi + A_hi*W_lo (~fp32 accuracy).
// T=1 collapses hete-attention: beta==1, wp==1 forever.

#define NTH 256

typedef __attribute__((ext_vector_type(8))) short bf16x8;   // 8 bf16 (4 VGPRs)
typedef __attribute__((ext_vector_type(4))) float floatx4;

__device__ __forceinline__ short f2bf(float f) {            // RNE fp32->bf16
    unsigned u = __builtin_bit_cast(unsigned, f);
    unsigned r = u + 0x7fffu + ((u >> 16) & 1u);
    return (short)(r >> 16);
}
__device__ __forceinline__ float bf2f_s(short h) {
    return __builtin_bit_cast(float, (unsigned)((unsigned short)h) << 16);
}

// split x -> hi + lo bf16 (hi=RNE(x), lo=RNE(x-hi)); ~16 mantissa bits total
__device__ __forceinline__ void split_pack8(float4 a, float4 b, bf16x8& hi, bf16x8& lo) {
    float v[8] = {a.x, a.y, a.z, a.w, b.x, b.y, b.z, b.w};
#pragma unroll
    for (int i = 0; i < 8; ++i) {
        short h = f2bf(v[i]);
        hi[i] = h;
        lo[i] = f2bf(v[i] - bf2f_s(h));
    }
}

__device__ __forceinline__ floatx4 mfma3(bf16x8 Ah, bf16x8 Al, bf16x8 Wh, bf16x8 Wl,
                                         floatx4 acc) {
    acc = __builtin_amdgcn_mfma_f32_16x16x32_bf16(Ah, Wh, acc, 0, 0, 0);
    acc = __builtin_amdgcn_mfma_f32_16x16x32_bf16(Al, Wh, acc, 0, 0, 0);
    acc = __builtin_amdgcn_mfma_f32_16x16x32_bf16(Ah, Wl, acc, 0, 0, 0);
    return acc;
}

__global__ __launch_bounds__(256, 3)
void disenhan_mfma(const float* __restrict__ user_table,
                   const float* __restrict__ item_table,
                   const float* __restrict__ W0u, const float* __restrict__ W0i,
                   const float* __restrict__ W1u, const float* __restrict__ W1i,
                   const int* __restrict__ uidx0, const int* __restrict__ uidx1,
                   const int* __restrict__ uidx2,
                   const int* __restrict__ iidx0, const int* __restrict__ iidx1,
                   const int* __restrict__ iidx2,
                   float* __restrict__ out, int B)
{
    constexpr float SCALE = 0.35355339059327373f;  // 1/sqrt(8)
    const int b = blockIdx.x, branch = blockIdx.y;
    const int tid = threadIdx.x;
    const int wv = tid >> 6, lane = tid & 63;
    const int quad = lane >> 4;   // MFMA k-block selector
    const int m16  = lane & 15;   // MFMA row (A) / col (B,D) selector

    const float *tab0, *tab1, *W1c, *W1n, *W0n;
    const int *idx0, *idx1, *idx2;
    if (branch == 0) { tab0 = user_table; tab1 = item_table;
                       idx0 = uidx0; idx1 = uidx1; idx2 = uidx2;
                       W1c = W1i; W1n = W1u; W0n = W0i; }
    else             { tab0 = item_table; tab1 = user_table;
                       idx0 = iidx0; idx1 = iidx1; idx2 = iidx2;
                       W1c = W1u; W1n = W1i; W0n = W0u; }

    __shared__ __align__(16) float sN[4][16 * 68];  // per-wave nh tile; ALSO pack scratch
    __shared__ float sC[16 * 68];     // hid (= c), pitch 68
    __shared__ float sH[16 * 68];     // htmp / h1, pitch 68
    __shared__ float sA[4][16 * 9];   // per-wave attention weights [n][k], pitch 9
    __shared__ float sE0[64];         // layer-0 center (e0)
    __shared__ float sH0[68];         // layer-0 htmp

    bf16x8* const pkL = (bf16x8*)&sN[0][0];  // 16KB packed-fragment region (aliased)

    // ---- cooperative pack: one 64x64 fp32 matrix -> hi/lo B-fragments in LDS ----
    // frag index f = nt*2+ks; pkL[(f*2+h)*64 + lane] = 8 bf16.
    auto pack_matrix = [&](const float* __restrict__ W) {
#pragma unroll
        for (int p = tid; p < 512; p += NTH) {
            int f = p >> 6, ln = p & 63;
            int q = ln >> 4, m = ln & 15, nt = f >> 1, ks = f & 1;
            bf16x8 fh, fl;
#pragma unroll
            for (int j = 0; j < 8; ++j) {
                float x = W[(ks * 32 + q * 8 + j) * 64 + nt * 16 + m];
                short h = f2bf(x);
                fh[j] = h;
                fl[j] = f2bf(x - bf2f_s(h));
            }
            pkL[(f * 2 + 0) * 64 + ln] = fh;
            pkL[(f * 2 + 1) * 64 + ln] = fl;
        }
    };

    bf16x8 wfh[4][2], wfl[4][2];
    auto read_frags = [&]() {   // 16 coalesced ds_read_b128 from the packed region
#pragma unroll
        for (int nt = 0; nt < 4; ++nt)
#pragma unroll
            for (int ks = 0; ks < 2; ++ks) {
                int f = nt * 2 + ks;
                wfh[nt][ks] = pkL[(f * 2 + 0) * 64 + lane];
                wfl[nt][ks] = pkL[(f * 2 + 1) * 64 + lane];
            }
    };

    // ---- routing: 3 iterations on one s-slot, intra-wave only ----
    auto routing = [&](const float* __restrict__ Nw, float* __restrict__ Hrow,
                       const float* __restrict__ Crow, float* __restrict__ Arow,
                       bool relu_last, float* __restrict__ outp) {
        const int mm = lane >> 3, kk = lane & 7;          // logits: n=mm,mm+8 ; facet kk
        const int r = lane >> 4, j4 = lane & 15, k2 = j4 >> 1;  // update mapping
#pragma unroll
        for (int it = 0; it < 3; ++it) {
            float4 ha = *(const float4*)&Hrow[kk * 8];
            float4 hb = *(const float4*)&Hrow[kk * 8 + 4];
            float4 na = *(const float4*)&Nw[mm * 68 + kk * 8];
            float4 nb = *(const float4*)&Nw[mm * 68 + kk * 8 + 4];
            float4 nc = *(const float4*)&Nw[(mm + 8) * 68 + kk * 8];
            float4 nd = *(const float4*)&Nw[(mm + 8) * 68 + kk * 8 + 4];
            float l0 = (ha.x*na.x + ha.y*na.y + ha.z*na.z + ha.w*na.w +
                        hb.x*nb.x + hb.y*nb.y + hb.z*nb.z + hb.w*nb.w) * SCALE;
            float l1 = (ha.x*nc.x + ha.y*nc.y + ha.z*nc.z + ha.w*nc.w +
                        hb.x*nd.x + hb.y*nd.y + hb.z*nd.z + hb.w*nd.w) * SCALE;
            float mx = fmaxf(l0, l1);
            mx = fmaxf(mx, __shfl_xor(mx, 8));
            mx = fmaxf(mx, __shfl_xor(mx, 16));
            mx = fmaxf(mx, __shfl_xor(mx, 32));
            float e0 = __expf(l0 - mx), e1 = __expf(l1 - mx);
            float sm = e0 + e1;
            sm += __shfl_xor(sm, 8); sm += __shfl_xor(sm, 16); sm += __shfl_xor(sm, 32);
            float inv = 1.0f / sm;
            Arow[mm * 9 + kk] = e0 * inv;
            Arow[(mm + 8) * 9 + kk] = e1 * inv;
            __builtin_amdgcn_wave_barrier();
            // z[j] = sum_n a[n][k(j)] * N[n][j] ; 4 n's per replica r, shuffle-reduced
            float4 z = {0.f, 0.f, 0.f, 0.f};
#pragma unroll
            for (int t = 0; t < 4; ++t) {
                float a = Arow[(4 * r + t) * 9 + k2];
                float4 nv = *(const float4*)&Nw[(4 * r + t) * 68 + j4 * 4];
                z.x = fmaf(a, nv.x, z.x); z.y = fmaf(a, nv.y, z.y);
                z.z = fmaf(a, nv.z, z.z); z.w = fmaf(a, nv.w, z.w);
            }
            z.x += __shfl_xor(z.x, 16); z.y += __shfl_xor(z.y, 16);
            z.z += __shfl_xor(z.z, 16); z.w += __shfl_xor(z.w, 16);
            z.x += __shfl_xor(z.x, 32); z.y += __shfl_xor(z.y, 32);
            z.z += __shfl_xor(z.z, 32); z.w += __shfl_xor(z.w, 32);
            if (r == 0) {
                float4 c = *(const float4*)&Crow[j4 * 4];
                float4 h = {c.x + z.x, c.y + z.y, c.z + z.z, c.w + z.w};
                if (relu_last && it == 2) {
                    h.x = fmaxf(h.x, 0.f); h.y = fmaxf(h.y, 0.f);
                    h.z = fmaxf(h.z, 0.f); h.w = fmaxf(h.w, 0.f);
                }
                *(float4*)&Hrow[j4 * 4] = h;
                if (outp && it == 2) *(float4*)&outp[j4 * 4] = h;
            }
            __builtin_amdgcn_wave_barrier();
        }
    };

    // ---- issue long-latency gathers early so they overlap the pack phases ----
    const float v0 = tab0[(long)idx0[b] * 64 + lane];       // e0 (wave 0, layer-0)
    const long g1 = (long)idx1[b * 16 + m16] * 64;
    const float* p1 = &tab1[g1 + quad * 8];
    float4 e1a = *(const float4*)p1;
    float4 e1b = *(const float4*)(p1 + 4);
    float4 e1c = *(const float4*)(p1 + 32);
    float4 e1d = *(const float4*)(p1 + 36);
    int gidx[4];
#pragma unroll
    for (int q = 0; q < 4; ++q)
        gidx[q] = idx2[b * 256 + (wv * 4 + q) * 16 + m16];
    float4 f0, f1, f2, f3;
    {
        const float* p = &tab0[(long)gidx[0] * 64 + quad * 8];
        f0 = *(const float4*)p;        f1 = *(const float4*)(p + 4);
        f2 = *(const float4*)(p + 32); f3 = *(const float4*)(p + 36);
    }

    // ================= stage W1c fragments =================
    pack_matrix(W1c);
    __syncthreads();           // B1: pack visible
    read_frags();
    __syncthreads();           // B2: all frag reads done; region reusable

    // ================= layer-1 pre-encode: hid = e1 @ W1c =================
    // (overlaps with W1n pack below — disjoint LDS: sC/sH vs sN)
    {
        bf16x8 A0h, A0l, A1h, A1l;
        split_pack8(e1a, e1b, A0h, A0l);
        split_pack8(e1c, e1d, A1h, A1l);
        floatx4 hacc[4];
#pragma unroll
        for (int nt = 0; nt < 4; ++nt) {
            hacc[nt] = (floatx4){0.f, 0.f, 0.f, 0.f};
            hacc[nt] = mfma3(A0h, A0l, wfh[nt][0], wfl[nt][0], hacc[nt]);
            hacc[nt] = mfma3(A1h, A1l, wfh[nt][1], wfl[nt][1], hacc[nt]);
        }
        // D: row = quad*4+reg, col = nt*16+m16. Wave w keeps rows w*4..w*4+3
        // (quad==wv lanes), which are exactly its own routing slots.
        if (quad == wv) {
#pragma unroll
            for (int nt = 0; nt < 4; ++nt)
#pragma unroll
                for (int rg = 0; rg < 4; ++rg) {
                    int row = quad * 4 + rg, col = nt * 16 + m16;
                    float v = hacc[nt][rg];
                    sC[row * 68 + col] = v;
                    sH[row * 68 + col] = v;
                }
        }
    }

    // ================= stage W1n fragments =================
    pack_matrix(W1n);
    __syncthreads();           // B3: pack visible
    read_frags();
    __syncthreads();           // B4: frag reads done; sN free for nh tiles

    // ================= layer-1 main: 4 s-slots per wave =================
#pragma unroll
    for (int q = 0; q < 4; ++q) {
        const int s = wv * 4 + q;
        bf16x8 A0h, A0l, A1h, A1l;
        split_pack8(f0, f1, A0h, A0l);
        split_pack8(f2, f3, A1h, A1l);
        if (q < 3) {  // prefetch next slot's A rows; consumed next iteration
            const float* p = &tab0[(long)gidx[q + 1] * 64 + quad * 8];
            f0 = *(const float4*)p;        f1 = *(const float4*)(p + 4);
            f2 = *(const float4*)(p + 32); f3 = *(const float4*)(p + 36);
        }
        floatx4 acc[4];
#pragma unroll
        for (int nt = 0; nt < 4; ++nt) {
            acc[nt] = (floatx4){0.f, 0.f, 0.f, 0.f};
            acc[nt] = mfma3(A0h, A0l, wfh[nt][0], wfl[nt][0], acc[nt]);
            acc[nt] = mfma3(A1h, A1l, wfh[nt][1], wfl[nt][1], acc[nt]);
        }
#pragma unroll
        for (int nt = 0; nt < 4; ++nt)
#pragma unroll
            for (int rg = 0; rg < 4; ++rg)
                sN[wv][(quad * 4 + rg) * 68 + nt * 16 + m16] = acc[nt][rg];
        __builtin_amdgcn_wave_barrier();
        routing(sN[wv], &sH[s * 68], &sC[s * 68], sA[wv], true, nullptr);
    }

    // ================= layer-0 =================
    __syncthreads();           // B5: all h1 rows visible
    if (wv == 0) {
        // W0n fragments: direct strided load+convert (one wave, tail — cheap)
#pragma unroll
        for (int nt = 0; nt < 4; ++nt)
#pragma unroll
            for (int ks = 0; ks < 2; ++ks) {
                const float* wp = &W0n[(ks * 32 + quad * 8) * 64 + nt * 16 + m16];
                bf16x8 fh, fl;
#pragma unroll
                for (int j = 0; j < 8; ++j) {
                    float x = wp[j * 64];
                    short h = f2bf(x);
                    fh[j] = h;
                    fl[j] = f2bf(x - bf2f_s(h));
                }
                wfh[nt][ks] = fh;
                wfl[nt][ks] = fl;
            }
        sE0[lane] = v0;
        sH0[lane] = v0;
        bf16x8 A0h, A0l, A1h, A1l;
        {
            const float* hp = &sH[m16 * 68];
            split_pack8(*(const float4*)&hp[quad * 8],
                        *(const float4*)&hp[quad * 8 + 4], A0h, A0l);
            split_pack8(*(const float4*)&hp[32 + quad * 8],
                        *(const float4*)&hp[32 + quad * 8 + 4], A1h, A1l);
        }
        floatx4 acc[4];
#pragma unroll
        for (int nt = 0; nt < 4; ++nt) {
            acc[nt] = (floatx4){0.f, 0.f, 0.f, 0.f};
            acc[nt] = mfma3(A0h, A0l, wfh[nt][0], wfl[nt][0], acc[nt]);
            acc[nt] = mfma3(A1h, A1l, wfh[nt][1], wfl[nt][1], acc[nt]);
        }
#pragma unroll
        for (int nt = 0; nt < 4; ++nt)
#pragma unroll
            for (int rg = 0; rg < 4; ++rg)
                sN[0][(quad * 4 + rg) * 68 + nt * 16 + m16] = acc[nt][rg];
        __builtin_amdgcn_wave_barrier();
        routing(sN[0], sH0, sE0, sA[0], false, &out[((long)branch * B + b) * 64]);
    }
}

extern "C" void kernel_launch(void* const* d_in, const int* in_sizes, int n_in,
                              void* d_out, int out_size, void* d_ws, size_t ws_size,
                              hipStream_t stream) {
    const float* user_table = (const float*)d_in[0];
    const float* item_table = (const float*)d_in[1];
    const float* W0u = (const float*)d_in[2];
    const float* W0i = (const float*)d_in[3];
    const float* W1u = (const float*)d_in[4];
    const float* W1i = (const float*)d_in[5];
    const int* uidx0 = (const int*)d_in[6];
    const int* uidx1 = (const int*)d_in[7];
    const int* uidx2 = (const int*)d_in[8];
    const int* iidx0 = (const int*)d_in[9];
    const int* iidx1 = (const int*)d_in[10];
    const int* iidx2 = (const int*)d_in[11];
    float* out = (float*)d_out;

    const int B = in_sizes[6];  // 2048
    dim3 grid(B, 2), block(NTH);
    hipLaunchKernelGGL(disenhan_mfma, grid, block, 0, stream,
                       user_table, item_table, W0u, W0i, W1u, W1i,
                       uidx0, uidx1, uidx2, iidx0, iidx1, iidx2, out, B);
}

// Round 9
// 204.618 us; speedup vs baseline: 1.0401x; 1.0401x over previous
//
#include <hip/hip_runtime.h>
#include <hip/hip_bf16.h>

// DisenHAN fused, MFMA split-bf16 edition, v5b (gfx950).
// v5b: fix compile — __hip_bfloat162 is not trivially copyable on this ROCm,
// so use __builtin_memcpy (register move) instead of __builtin_bit_cast.
// Base = round-6 v3 (separate 4-block pack kernel -> pk in d_ws; main kernel
// launch_bounds(256,3)).
// v5 changes:
//  (1) bf16 conversions via v_cvt_pk_bf16_f32 (__float22bfloat162_rn) for the
//      hi/lo split: ~24 VALU per 8 elements (was ~48). The 3-pass product
//      (Ah+Al)(Wh+Wl)-Al*Wl is insensitive to conversion rounding mode.
//  (2) routing processes 2 s-slots interleaved per wave (pairs (0,1),(2,3)):
//      2x independent work between dependent shuffle-reduce hops. sN holds
//      2 tiles/wave (LDS 47.5KB, still 3 blocks/CU).
// 3-pass split-bf16 MFMA: A_hi*W_hi + A_lo*W_hi + A_hi*W_lo (~fp32 accuracy).
// T=1 collapses hete-attention: beta==1, wp==1 forever.

#define NTH 256

typedef __attribute__((ext_vector_type(8))) short bf16x8;   // 8 bf16 (4 VGPRs)
typedef __attribute__((ext_vector_type(4))) float floatx4;

__device__ __forceinline__ short f2bf(float f) {            // RNE fp32->bf16 (pack kernel)
    unsigned u = __builtin_bit_cast(unsigned, f);
    unsigned r = u + 0x7fffu + ((u >> 16) & 1u);
    return (short)(r >> 16);
}
__device__ __forceinline__ float bf2f_s(short h) {
    return __builtin_bit_cast(float, (unsigned)((unsigned short)h) << 16);
}

// pack two fp32 -> one dword of two bf16 (v_cvt_pk_bf16_f32)
__device__ __forceinline__ unsigned cvt_pk_bf16(float x0, float x1) {
    __hip_bfloat162 h2 = __float22bfloat162_rn(make_float2(x0, x1));
    unsigned u;
    __builtin_memcpy(&u, &h2, 4);
    return u;
}

// split x -> hi + lo bf16 via packed cvt
__device__ __forceinline__ void split_pack8(float4 a, float4 b, bf16x8& hi, bf16x8& lo) {
    float v[8] = {a.x, a.y, a.z, a.w, b.x, b.y, b.z, b.w};
    unsigned hp[4], lp[4];
#pragma unroll
    for (int i = 0; i < 4; ++i) {
        float x0 = v[2 * i], x1 = v[2 * i + 1];
        unsigned hb = cvt_pk_bf16(x0, x1);
        hp[i] = hb;
        float r0 = x0 - __builtin_bit_cast(float, hb << 16);
        float r1 = x1 - __builtin_bit_cast(float, hb & 0xffff0000u);
        lp[i] = cvt_pk_bf16(r0, r1);
    }
    hi = __builtin_bit_cast(bf16x8, (uint4){hp[0], hp[1], hp[2], hp[3]});
    lo = __builtin_bit_cast(bf16x8, (uint4){lp[0], lp[1], lp[2], lp[3]});
}

__device__ __forceinline__ floatx4 mfma3(bf16x8 Ah, bf16x8 Al, bf16x8 Wh, bf16x8 Wl,
                                         floatx4 acc) {
    acc = __builtin_amdgcn_mfma_f32_16x16x32_bf16(Ah, Wh, acc, 0, 0, 0);
    acc = __builtin_amdgcn_mfma_f32_16x16x32_bf16(Al, Wh, acc, 0, 0, 0);
    acc = __builtin_amdgcn_mfma_f32_16x16x32_bf16(Ah, Wl, acc, 0, 0, 0);
    return acc;
}

// ---- setup: pack 4 weight matrices into B-fragment order, hi/lo split ----
// layout: frag16[ ((w*4+nt)*2+ks)*2+h ][ lane ] = 8 bf16 (16B), coalesced.
__global__ void pack_weights(const float* __restrict__ W0u, const float* __restrict__ W0i,
                             const float* __restrict__ W1u, const float* __restrict__ W1i,
                             short* __restrict__ pk) {
    const float* Ws[4] = {W0u, W0i, W1u, W1i};
    const int w = blockIdx.x;
    const int wv = threadIdx.x >> 6, lane = threadIdx.x & 63;
    const int quad = lane >> 4, m16 = lane & 15;
    const int nt = wv;
    const float* W = Ws[w];
#pragma unroll
    for (int ks = 0; ks < 2; ++ks) {
        bf16x8 fh, fl;
#pragma unroll
        for (int j = 0; j < 8; ++j) {
            float x = W[(ks * 32 + quad * 8 + j) * 64 + nt * 16 + m16];
            short h = f2bf(x);
            fh[j] = h;
            fl[j] = f2bf(x - bf2f_s(h));
        }
        long base = (long)(((w * 4 + nt) * 2 + ks) * 2) * 64 + lane;
        ((bf16x8*)pk)[base] = fh;         // h=0 (hi)
        ((bf16x8*)pk)[base + 64] = fl;    // h=1 (lo)
    }
}

__global__ __launch_bounds__(256, 3)
void disenhan_mfma(const float* __restrict__ user_table,
                   const float* __restrict__ item_table,
                   const bf16x8* __restrict__ pk,
                   const int* __restrict__ uidx0, const int* __restrict__ uidx1,
                   const int* __restrict__ uidx2,
                   const int* __restrict__ iidx0, const int* __restrict__ iidx1,
                   const int* __restrict__ iidx2,
                   float* __restrict__ out, int B)
{
    constexpr float SCALE = 0.35355339059327373f;  // 1/sqrt(8)
    const int b = blockIdx.x, branch = blockIdx.y;
    const int tid = threadIdx.x;
    const int wv = tid >> 6, lane = tid & 63;
    const int quad = lane >> 4;   // MFMA k-block selector
    const int m16  = lane & 15;   // MFMA row (A) / col (B,D) selector

    // matrix ids in pk: 0=W0u 1=W0i 2=W1u 3=W1i
    const float *tab0, *tab1;
    const int *idx0, *idx1, *idx2;
    int w1c_id, w1n_id, w0n_id;
    if (branch == 0) { tab0 = user_table; tab1 = item_table;
                       idx0 = uidx0; idx1 = uidx1; idx2 = uidx2;
                       w1c_id = 3; w1n_id = 2; w0n_id = 1; }
    else             { tab0 = item_table; tab1 = user_table;
                       idx0 = iidx0; idx1 = iidx1; idx2 = iidx2;
                       w1c_id = 2; w1n_id = 3; w0n_id = 0; }

    __shared__ float sN[4][2][16 * 68]; // per-wave nh tiles, 2 slots interleaved
    __shared__ float sC[16 * 68];       // hid (= c), pitch 68
    __shared__ float sH[16 * 68];       // htmp / h1, pitch 68
    __shared__ float sA[4][2][16 * 9];  // per-wave attention weights [slot][n][k]
    __shared__ float sE0[64];           // layer-0 center (e0)
    __shared__ float sH0[68];           // layer-0 htmp

    // e0 prefetch (consumed by wave 0 at the end; loaded by all, uniform)
    const float v0 = tab0[(long)idx0[b] * 64 + lane];

    // ---- B-fragment loader: 16 coalesced 16B loads from the packed buffer ----
    bf16x8 wfh[4][2], wfl[4][2];
    auto load_wfrag = [&](int w) {
#pragma unroll
        for (int nt = 0; nt < 4; ++nt)
#pragma unroll
            for (int ks = 0; ks < 2; ++ks) {
                long base = (long)(((w * 4 + nt) * 2 + ks) * 2) * 64 + lane;
                wfh[nt][ks] = pk[base];
                wfl[nt][ks] = pk[base + 64];
            }
    };

    const int mm = lane >> 3, kk = lane & 7;                // logits lane map
    const int r = lane >> 4, j4 = lane & 15, k2 = j4 >> 1;  // update lane map

    // ---- single-slot routing (layer-0) ----
    auto routing1 = [&](const float* __restrict__ Nw, float* __restrict__ Hrow,
                        const float* __restrict__ Crow, float* __restrict__ Arow,
                        float* __restrict__ outp) {
#pragma unroll
        for (int it = 0; it < 3; ++it) {
            float4 ha = *(const float4*)&Hrow[kk * 8];
            float4 hb = *(const float4*)&Hrow[kk * 8 + 4];
            float4 na = *(const float4*)&Nw[mm * 68 + kk * 8];
            float4 nb = *(const float4*)&Nw[mm * 68 + kk * 8 + 4];
            float4 nc = *(const float4*)&Nw[(mm + 8) * 68 + kk * 8];
            float4 nd = *(const float4*)&Nw[(mm + 8) * 68 + kk * 8 + 4];
            float l0 = (ha.x*na.x + ha.y*na.y + ha.z*na.z + ha.w*na.w +
                        hb.x*nb.x + hb.y*nb.y + hb.z*nb.z + hb.w*nb.w) * SCALE;
            float l1 = (ha.x*nc.x + ha.y*nc.y + ha.z*nc.z + ha.w*nc.w +
                        hb.x*nd.x + hb.y*nd.y + hb.z*nd.z + hb.w*nd.w) * SCALE;
            float mx = fmaxf(l0, l1);
            mx = fmaxf(mx, __shfl_xor(mx, 8));
            mx = fmaxf(mx, __shfl_xor(mx, 16));
            mx = fmaxf(mx, __shfl_xor(mx, 32));
            float e0 = __expf(l0 - mx), e1 = __expf(l1 - mx);
            float sm = e0 + e1;
            sm += __shfl_xor(sm, 8); sm += __shfl_xor(sm, 16); sm += __shfl_xor(sm, 32);
            float inv = 1.0f / sm;
            Arow[mm * 9 + kk] = e0 * inv;
            Arow[(mm + 8) * 9 + kk] = e1 * inv;
            __builtin_amdgcn_wave_barrier();
            float4 z = {0.f, 0.f, 0.f, 0.f};
#pragma unroll
            for (int t = 0; t < 4; ++t) {
                float a = Arow[(4 * r + t) * 9 + k2];
                float4 nv = *(const float4*)&Nw[(4 * r + t) * 68 + j4 * 4];
                z.x = fmaf(a, nv.x, z.x); z.y = fmaf(a, nv.y, z.y);
                z.z = fmaf(a, nv.z, z.z); z.w = fmaf(a, nv.w, z.w);
            }
            z.x += __shfl_xor(z.x, 16); z.y += __shfl_xor(z.y, 16);
            z.z += __shfl_xor(z.z, 16); z.w += __shfl_xor(z.w, 16);
            z.x += __shfl_xor(z.x, 32); z.y += __shfl_xor(z.y, 32);
            z.z += __shfl_xor(z.z, 32); z.w += __shfl_xor(z.w, 32);
            if (r == 0) {
                float4 c = *(const float4*)&Crow[j4 * 4];
                float4 h = {c.x + z.x, c.y + z.y, c.z + z.z, c.w + z.w};
                *(float4*)&Hrow[j4 * 4] = h;
                if (outp && it == 2) *(float4*)&outp[j4 * 4] = h;
            }
            __builtin_amdgcn_wave_barrier();
        }
    };

    // ---- 2-slot interleaved routing (layer-1): 2x ILP on the shuffle chains ----
    auto routing2 = [&](const float* __restrict__ N0, const float* __restrict__ N1,
                        float* __restrict__ H0, float* __restrict__ H1,
                        const float* __restrict__ C0, const float* __restrict__ C1,
                        float* __restrict__ A0, float* __restrict__ A1) {
#pragma unroll
        for (int it = 0; it < 3; ++it) {
            float l0a, l1a, l0b, l1b;
            {
                float4 ha = *(const float4*)&H0[kk * 8];
                float4 hb = *(const float4*)&H0[kk * 8 + 4];
                float4 na = *(const float4*)&N0[mm * 68 + kk * 8];
                float4 nb = *(const float4*)&N0[mm * 68 + kk * 8 + 4];
                float4 nc = *(const float4*)&N0[(mm + 8) * 68 + kk * 8];
                float4 nd = *(const float4*)&N0[(mm + 8) * 68 + kk * 8 + 4];
                l0a = (ha.x*na.x + ha.y*na.y + ha.z*na.z + ha.w*na.w +
                       hb.x*nb.x + hb.y*nb.y + hb.z*nb.z + hb.w*nb.w) * SCALE;
                l1a = (ha.x*nc.x + ha.y*nc.y + ha.z*nc.z + ha.w*nc.w +
                       hb.x*nd.x + hb.y*nd.y + hb.z*nd.z + hb.w*nd.w) * SCALE;
            }
            {
                float4 ha = *(const float4*)&H1[kk * 8];
                float4 hb = *(const float4*)&H1[kk * 8 + 4];
                float4 na = *(const float4*)&N1[mm * 68 + kk * 8];
                float4 nb = *(const float4*)&N1[mm * 68 + kk * 8 + 4];
                float4 nc = *(const float4*)&N1[(mm + 8) * 68 + kk * 8];
                float4 nd = *(const float4*)&N1[(mm + 8) * 68 + kk * 8 + 4];
                l0b = (ha.x*na.x + ha.y*na.y + ha.z*na.z + ha.w*na.w +
                       hb.x*nb.x + hb.y*nb.y + hb.z*nb.z + hb.w*nb.w) * SCALE;
                l1b = (ha.x*nc.x + ha.y*nc.y + ha.z*nc.z + ha.w*nc.w +
                       hb.x*nd.x + hb.y*nd.y + hb.z*nd.z + hb.w*nd.w) * SCALE;
            }
            float mxa = fmaxf(l0a, l1a), mxb = fmaxf(l0b, l1b);
            mxa = fmaxf(mxa, __shfl_xor(mxa, 8));  mxb = fmaxf(mxb, __shfl_xor(mxb, 8));
            mxa = fmaxf(mxa, __shfl_xor(mxa, 16)); mxb = fmaxf(mxb, __shfl_xor(mxb, 16));
            mxa = fmaxf(mxa, __shfl_xor(mxa, 32)); mxb = fmaxf(mxb, __shfl_xor(mxb, 32));
            float e0a = __expf(l0a - mxa), e1a = __expf(l1a - mxa);
            float e0b = __expf(l0b - mxb), e1b = __expf(l1b - mxb);
            float sma = e0a + e1a, smb = e0b + e1b;
            sma += __shfl_xor(sma, 8);  smb += __shfl_xor(smb, 8);
            sma += __shfl_xor(sma, 16); smb += __shfl_xor(smb, 16);
            sma += __shfl_xor(sma, 32); smb += __shfl_xor(smb, 32);
            float inva = 1.0f / sma, invb = 1.0f / smb;
            A0[mm * 9 + kk] = e0a * inva;
            A0[(mm + 8) * 9 + kk] = e1a * inva;
            A1[mm * 9 + kk] = e0b * invb;
            A1[(mm + 8) * 9 + kk] = e1b * invb;
            __builtin_amdgcn_wave_barrier();
            float4 za = {0.f, 0.f, 0.f, 0.f}, zb = {0.f, 0.f, 0.f, 0.f};
#pragma unroll
            for (int t = 0; t < 4; ++t) {
                float aa = A0[(4 * r + t) * 9 + k2];
                float4 nva = *(const float4*)&N0[(4 * r + t) * 68 + j4 * 4];
                za.x = fmaf(aa, nva.x, za.x); za.y = fmaf(aa, nva.y, za.y);
                za.z = fmaf(aa, nva.z, za.z); za.w = fmaf(aa, nva.w, za.w);
                float ab = A1[(4 * r + t) * 9 + k2];
                float4 nvb = *(const float4*)&N1[(4 * r + t) * 68 + j4 * 4];
                zb.x = fmaf(ab, nvb.x, zb.x); zb.y = fmaf(ab, nvb.y, zb.y);
                zb.z = fmaf(ab, nvb.z, zb.z); zb.w = fmaf(ab, nvb.w, zb.w);
            }
            za.x += __shfl_xor(za.x, 16); zb.x += __shfl_xor(zb.x, 16);
            za.y += __shfl_xor(za.y, 16); zb.y += __shfl_xor(zb.y, 16);
            za.z += __shfl_xor(za.z, 16); zb.z += __shfl_xor(zb.z, 16);
            za.w += __shfl_xor(za.w, 16); zb.w += __shfl_xor(zb.w, 16);
            za.x += __shfl_xor(za.x, 32); zb.x += __shfl_xor(zb.x, 32);
            za.y += __shfl_xor(za.y, 32); zb.y += __shfl_xor(zb.y, 32);
            za.z += __shfl_xor(za.z, 32); zb.z += __shfl_xor(zb.z, 32);
            za.w += __shfl_xor(za.w, 32); zb.w += __shfl_xor(zb.w, 32);
            if (r == 0) {
                float4 ca = *(const float4*)&C0[j4 * 4];
                float4 haf = {ca.x + za.x, ca.y + za.y, ca.z + za.z, ca.w + za.w};
                float4 cb = *(const float4*)&C1[j4 * 4];
                float4 hbf = {cb.x + zb.x, cb.y + zb.y, cb.z + zb.z, cb.w + zb.w};
                if (it == 2) {  // h1 = relu(htmp) on the last iteration
                    haf.x = fmaxf(haf.x, 0.f); haf.y = fmaxf(haf.y, 0.f);
                    haf.z = fmaxf(haf.z, 0.f); haf.w = fmaxf(haf.w, 0.f);
                    hbf.x = fmaxf(hbf.x, 0.f); hbf.y = fmaxf(hbf.y, 0.f);
                    hbf.z = fmaxf(hbf.z, 0.f); hbf.w = fmaxf(hbf.w, 0.f);
                }
                *(float4*)&H0[j4 * 4] = haf;
                *(float4*)&H1[j4 * 4] = hbf;
            }
            __builtin_amdgcn_wave_barrier();
        }
    };

    // ---- 16x64 tile matmul into one sN tile (24 MFMAs) ----
    auto matmul_tile = [&](float4 f0, float4 f1, float4 f2, float4 f3,
                           float* __restrict__ Nw) {
        bf16x8 A0h, A0l, A1h, A1l;
        split_pack8(f0, f1, A0h, A0l);
        split_pack8(f2, f3, A1h, A1l);
        floatx4 acc[4];
#pragma unroll
        for (int nt = 0; nt < 4; ++nt) {
            acc[nt] = (floatx4){0.f, 0.f, 0.f, 0.f};
            acc[nt] = mfma3(A0h, A0l, wfh[nt][0], wfl[nt][0], acc[nt]);
            acc[nt] = mfma3(A1h, A1l, wfh[nt][1], wfl[nt][1], acc[nt]);
        }
#pragma unroll
        for (int nt = 0; nt < 4; ++nt)
#pragma unroll
            for (int rg = 0; rg < 4; ++rg)
                Nw[(quad * 4 + rg) * 68 + nt * 16 + m16] = acc[nt][rg];
    };

    // ---- issue long-latency gathers early ----
    const long g1 = (long)idx1[b * 16 + m16] * 64;
    const float* p1 = &tab1[g1 + quad * 8];
    float4 e1a = *(const float4*)p1;
    float4 e1b = *(const float4*)(p1 + 4);
    float4 e1c = *(const float4*)(p1 + 32);
    float4 e1d = *(const float4*)(p1 + 36);
    int gidx[4];
#pragma unroll
    for (int q = 0; q < 4; ++q)
        gidx[q] = idx2[b * 256 + (wv * 4 + q) * 16 + m16];

    // ================= layer-1 pre-encode: hid = e1 @ W1c =================
    load_wfrag(w1c_id);
    {
        bf16x8 A0h, A0l, A1h, A1l;
        split_pack8(e1a, e1b, A0h, A0l);
        split_pack8(e1c, e1d, A1h, A1l);
        floatx4 hacc[4];
#pragma unroll
        for (int nt = 0; nt < 4; ++nt) {
            hacc[nt] = (floatx4){0.f, 0.f, 0.f, 0.f};
            hacc[nt] = mfma3(A0h, A0l, wfh[nt][0], wfl[nt][0], hacc[nt]);
            hacc[nt] = mfma3(A1h, A1l, wfh[nt][1], wfl[nt][1], hacc[nt]);
        }
        // D: row = quad*4+reg, col = nt*16+m16. Wave w keeps rows w*4..w*4+3
        // (quad==wv lanes) — exactly its own routing slots.
        if (quad == wv) {
#pragma unroll
            for (int nt = 0; nt < 4; ++nt)
#pragma unroll
                for (int rg = 0; rg < 4; ++rg) {
                    int row = quad * 4 + rg, col = nt * 16 + m16;
                    float v = hacc[nt][rg];
                    sC[row * 68 + col] = v;
                    sH[row * 68 + col] = v;
                }
        }
    }

    // ================= layer-1 main: 2 pairs of slots per wave =================
    float4 g0, g1v, g2, g3, h0, h1, h2, h3;
    {
        const float* p = &tab0[(long)gidx[0] * 64 + quad * 8];
        g0 = *(const float4*)p;        g1v = *(const float4*)(p + 4);
        g2 = *(const float4*)(p + 32); g3 = *(const float4*)(p + 36);
        const float* p2 = &tab0[(long)gidx[1] * 64 + quad * 8];
        h0 = *(const float4*)p2;        h1 = *(const float4*)(p2 + 4);
        h2 = *(const float4*)(p2 + 32); h3 = *(const float4*)(p2 + 36);
    }
    load_wfrag(w1n_id);
#pragma unroll
    for (int pr = 0; pr < 2; ++pr) {
        const int s0 = wv * 4 + 2 * pr, s1 = s0 + 1;
        matmul_tile(g0, g1v, g2, g3, sN[wv][0]);
        matmul_tile(h0, h1, h2, h3, sN[wv][1]);
        if (pr == 0) {  // prefetch pair-1's A rows; hidden under routing below
            const float* p = &tab0[(long)gidx[2] * 64 + quad * 8];
            g0 = *(const float4*)p;        g1v = *(const float4*)(p + 4);
            g2 = *(const float4*)(p + 32); g3 = *(const float4*)(p + 36);
            const float* p2 = &tab0[(long)gidx[3] * 64 + quad * 8];
            h0 = *(const float4*)p2;        h1 = *(const float4*)(p2 + 4);
            h2 = *(const float4*)(p2 + 32); h3 = *(const float4*)(p2 + 36);
        }
        __builtin_amdgcn_wave_barrier();
        routing2(sN[wv][0], sN[wv][1], &sH[s0 * 68], &sH[s1 * 68],
                 &sC[s0 * 68], &sC[s1 * 68], sA[wv][0], sA[wv][1]);
    }

    // ================= layer-0 =================
    __syncthreads();   // the only block barrier: all h1 rows visible
    if (wv == 0) {
        load_wfrag(w0n_id);
        sE0[lane] = v0;
        sH0[lane] = v0;
        bf16x8 A0h, A0l, A1h, A1l;
        {
            const float* hp = &sH[m16 * 68];
            split_pack8(*(const float4*)&hp[quad * 8],
                        *(const float4*)&hp[quad * 8 + 4], A0h, A0l);
            split_pack8(*(const float4*)&hp[32 + quad * 8],
                        *(const float4*)&hp[32 + quad * 8 + 4], A1h, A1l);
        }
        floatx4 acc[4];
#pragma unroll
        for (int nt = 0; nt < 4; ++nt) {
            acc[nt] = (floatx4){0.f, 0.f, 0.f, 0.f};
            acc[nt] = mfma3(A0h, A0l, wfh[nt][0], wfl[nt][0], acc[nt]);
            acc[nt] = mfma3(A1h, A1l, wfh[nt][1], wfl[nt][1], acc[nt]);
        }
#pragma unroll
        for (int nt = 0; nt < 4; ++nt)
#pragma unroll
            for (int rg = 0; rg < 4; ++rg)
                sN[0][0][(quad * 4 + rg) * 68 + nt * 16 + m16] = acc[nt][rg];
        __builtin_amdgcn_wave_barrier();
        routing1(sN[0][0], sH0, sE0, sA[0][0], &out[((long)branch * B + b) * 64]);
    }
}

extern "C" void kernel_launch(void* const* d_in, const int* in_sizes, int n_in,
                              void* d_out, int out_size, void* d_ws, size_t ws_size,
                              hipStream_t stream) {
    const float* user_table = (const float*)d_in[0];
    const float* item_table = (const float*)d_in[1];
    const float* W0u = (const float*)d_in[2];
    const float* W0i = (const float*)d_in[3];
    const float* W1u = (const float*)d_in[4];
    const float* W1i = (const float*)d_in[5];
    const int* uidx0 = (const int*)d_in[6];
    const int* uidx1 = (const int*)d_in[7];
    const int* uidx2 = (const int*)d_in[8];
    const int* iidx0 = (const int*)d_in[9];
    const int* iidx1 = (const int*)d_in[10];
    const int* iidx2 = (const int*)d_in[11];
    float* out = (float*)d_out;
    short* pk = (short*)d_ws;   // 4 matrices * 16 frags * 64 lanes * 16B = 64 KB

    const int B = in_sizes[6];  // 2048
    hipLaunchKernelGGL(pack_weights, dim3(4), dim3(256), 0, stream,
                       W0u, W0i, W1u, W1i, pk);
    dim3 grid(B, 2), block(NTH);
    hipLaunchKernelGGL(disenhan_mfma, grid, block, 0, stream,
                       user_table, item_table, (const bf16x8*)pk,
                       uidx0, uidx1, uidx2, iidx0, iidx1, iidx2, out, B);
}

// Round 10
// 187.482 us; speedup vs baseline: 1.1352x; 1.0914x over previous
//
#include <hip/hip_runtime.h>
#include <hip/hip_bf16.h>

// DisenHAN fused, MFMA split-bf16 edition, v6 (gfx950).
// v6: register-resident routing. Round-9 showed 2-slot interleave doubled
// bank conflicts (4.8M->9.26M) and the LDS pipe (~65% busy by instruction
// count) is the bottleneck. New routing lane map: lane(r=lane>>4, j4=lane&15)
// owns cols 4j4..4j4+3 (facet k2=j4>>1) and rows 4r..4r+3. Per iteration:
//   - ONE tile pass: Nv[t] = N[4r+t][4j4..] (4x b128), reused for logits AND z
//   - logits: dot4(h4,Nv[t]) pair-reduced with shfl_xor(1) -> e[4r+t][k2]
//   - softmax over n: in-reg over t + shfl_xor(16/32) over r
//   - a[4r+t][k2] is ALREADY in the lane that z needs it in (no sA round-trip)
//   - z = sum_t a[t]*Nv[t], reduced over r via shfl_xor(16/32)
//   - htmp h4 stays in registers across iterations (no H LDS traffic)
// LDS per slot-iter: 11xb128+6xb32 -> 4xb128 (+1 c-read & 1 h-write per slot).
// Base retained: separate 4-block pack kernel (pk in d_ws), cvt_pk split,
// launch_bounds(256,3), early gathers, per-slot prefetch.
// 3-pass split-bf16 MFMA: A_hi*W_hi + A_lo*W_hi + A_hi*W_lo (~fp32 accuracy).
// T=1 collapses hete-attention: beta==1, wp==1 forever.

#define NTH 256

typedef __attribute__((ext_vector_type(8))) short bf16x8;   // 8 bf16 (4 VGPRs)
typedef __attribute__((ext_vector_type(4))) float floatx4;

__device__ __forceinline__ short f2bf(float f) {            // RNE fp32->bf16 (pack kernel)
    unsigned u = __builtin_bit_cast(unsigned, f);
    unsigned r = u + 0x7fffu + ((u >> 16) & 1u);
    return (short)(r >> 16);
}
__device__ __forceinline__ float bf2f_s(short h) {
    return __builtin_bit_cast(float, (unsigned)((unsigned short)h) << 16);
}

// pack two fp32 -> one dword of two bf16 (v_cvt_pk_bf16_f32)
__device__ __forceinline__ unsigned cvt_pk_bf16(float x0, float x1) {
    __hip_bfloat162 h2 = __float22bfloat162_rn(make_float2(x0, x1));
    unsigned u;
    __builtin_memcpy(&u, &h2, 4);
    return u;
}

// split x -> hi + lo bf16 via packed cvt
__device__ __forceinline__ void split_pack8(float4 a, float4 b, bf16x8& hi, bf16x8& lo) {
    float v[8] = {a.x, a.y, a.z, a.w, b.x, b.y, b.z, b.w};
    unsigned hp[4], lp[4];
#pragma unroll
    for (int i = 0; i < 4; ++i) {
        float x0 = v[2 * i], x1 = v[2 * i + 1];
        unsigned hb = cvt_pk_bf16(x0, x1);
        hp[i] = hb;
        float r0 = x0 - __builtin_bit_cast(float, hb << 16);
        float r1 = x1 - __builtin_bit_cast(float, hb & 0xffff0000u);
        lp[i] = cvt_pk_bf16(r0, r1);
    }
    hi = __builtin_bit_cast(bf16x8, (uint4){hp[0], hp[1], hp[2], hp[3]});
    lo = __builtin_bit_cast(bf16x8, (uint4){lp[0], lp[1], lp[2], lp[3]});
}

__device__ __forceinline__ floatx4 mfma3(bf16x8 Ah, bf16x8 Al, bf16x8 Wh, bf16x8 Wl,
                                         floatx4 acc) {
    acc = __builtin_amdgcn_mfma_f32_16x16x32_bf16(Ah, Wh, acc, 0, 0, 0);
    acc = __builtin_amdgcn_mfma_f32_16x16x32_bf16(Al, Wh, acc, 0, 0, 0);
    acc = __builtin_amdgcn_mfma_f32_16x16x32_bf16(Ah, Wl, acc, 0, 0, 0);
    return acc;
}

// ---- setup: pack 4 weight matrices into B-fragment order, hi/lo split ----
__global__ void pack_weights(const float* __restrict__ W0u, const float* __restrict__ W0i,
                             const float* __restrict__ W1u, const float* __restrict__ W1i,
                             short* __restrict__ pk) {
    const float* Ws[4] = {W0u, W0i, W1u, W1i};
    const int w = blockIdx.x;
    const int wv = threadIdx.x >> 6, lane = threadIdx.x & 63;
    const int quad = lane >> 4, m16 = lane & 15;
    const int nt = wv;
    const float* W = Ws[w];
#pragma unroll
    for (int ks = 0; ks < 2; ++ks) {
        bf16x8 fh, fl;
#pragma unroll
        for (int j = 0; j < 8; ++j) {
            float x = W[(ks * 32 + quad * 8 + j) * 64 + nt * 16 + m16];
            short h = f2bf(x);
            fh[j] = h;
            fl[j] = f2bf(x - bf2f_s(h));
        }
        long base = (long)(((w * 4 + nt) * 2 + ks) * 2) * 64 + lane;
        ((bf16x8*)pk)[base] = fh;
        ((bf16x8*)pk)[base + 64] = fl;
    }
}

__global__ __launch_bounds__(256, 3)
void disenhan_mfma(const float* __restrict__ user_table,
                   const float* __restrict__ item_table,
                   const bf16x8* __restrict__ pk,
                   const int* __restrict__ uidx0, const int* __restrict__ uidx1,
                   const int* __restrict__ uidx2,
                   const int* __restrict__ iidx0, const int* __restrict__ iidx1,
                   const int* __restrict__ iidx2,
                   float* __restrict__ out, int B)
{
    constexpr float SCALE = 0.35355339059327373f;  // 1/sqrt(8)
    const int b = blockIdx.x, branch = blockIdx.y;
    const int tid = threadIdx.x;
    const int wv = tid >> 6, lane = tid & 63;
    const int quad = lane >> 4;   // MFMA k-block selector
    const int m16  = lane & 15;   // MFMA row (A) / col (B,D) selector
    const int rr   = lane >> 4;   // routing: row group (rows 4rr..4rr+3)
    const int j4   = lane & 15;   // routing: col group (cols 4j4..4j4+3)

    // matrix ids in pk: 0=W0u 1=W0i 2=W1u 3=W1i
    const float *tab0, *tab1;
    const int *idx0, *idx1, *idx2;
    int w1c_id, w1n_id, w0n_id;
    if (branch == 0) { tab0 = user_table; tab1 = item_table;
                       idx0 = uidx0; idx1 = uidx1; idx2 = uidx2;
                       w1c_id = 3; w1n_id = 2; w0n_id = 1; }
    else             { tab0 = item_table; tab1 = user_table;
                       idx0 = iidx0; idx1 = iidx1; idx2 = iidx2;
                       w1c_id = 2; w1n_id = 3; w0n_id = 0; }

    __shared__ float sN[4][16 * 68];  // per-wave nh tile (fp32, pitch 68)
    __shared__ float sC[16 * 68];     // hid (= c), pitch 68
    __shared__ float sH[16 * 68];     // h1 (written once per slot at the end)
    __shared__ float sE0[64];         // layer-0 center (e0)

    // e0 prefetch (consumed by wave 0 at the end; loaded by all, uniform)
    const float v0 = tab0[(long)idx0[b] * 64 + lane];

    // ---- B-fragment loader: 16 coalesced 16B loads from the packed buffer ----
    bf16x8 wfh[4][2], wfl[4][2];
    auto load_wfrag = [&](int w) {
#pragma unroll
        for (int nt = 0; nt < 4; ++nt)
#pragma unroll
            for (int ks = 0; ks < 2; ++ks) {
                long base = (long)(((w * 4 + nt) * 2 + ks) * 2) * 64 + lane;
                wfh[nt][ks] = pk[base];
                wfl[nt][ks] = pk[base + 64];
            }
    };

    // ---- register-resident routing: 3 iterations on one s-slot ----
    // Nw: wave's 16x64 tile in LDS (pitch 68). c4 = hid[s][4j4..4j4+3].
    // On exit h4 is final htmp; caller (r==0 lanes) stores it.
    auto routing_reg = [&](const float* __restrict__ Nw, float4 c4, bool relu_last)
        -> float4 {
        float4 h4 = c4;   // iter-0 htmp = hid
#pragma unroll
        for (int it = 0; it < 3; ++it) {
            float4 Nv[4];
#pragma unroll
            for (int t = 0; t < 4; ++t)
                Nv[t] = *(const float4*)&Nw[(4 * rr + t) * 68 + 4 * j4];
            // logits e[4rr+t][k2]: dot over this lane's 4 cols + pair lane's 4
            float pp[4];
#pragma unroll
            for (int t = 0; t < 4; ++t) {
                float d = h4.x * Nv[t].x + h4.y * Nv[t].y +
                          h4.z * Nv[t].z + h4.w * Nv[t].w;
                d += __shfl_xor(d, 1);        // + other half of the octet
                pp[t] = d * SCALE;
            }
            // softmax over n (16 rows): in-reg over t, shfl over rr
            float m = fmaxf(fmaxf(pp[0], pp[1]), fmaxf(pp[2], pp[3]));
            m = fmaxf(m, __shfl_xor(m, 16));
            m = fmaxf(m, __shfl_xor(m, 32));
            float e0 = __expf(pp[0] - m), e1 = __expf(pp[1] - m);
            float e2 = __expf(pp[2] - m), e3 = __expf(pp[3] - m);
            float sm = (e0 + e1) + (e2 + e3);
            sm += __shfl_xor(sm, 16);
            sm += __shfl_xor(sm, 32);
            float inv = 1.0f / sm;
            float a0 = e0 * inv, a1 = e1 * inv, a2 = e2 * inv, a3 = e3 * inv;
            // z[4j4..] partial over rows 4rr..4rr+3, then reduce over rr
            float4 z;
            z.x = a0 * Nv[0].x; z.y = a0 * Nv[0].y; z.z = a0 * Nv[0].z; z.w = a0 * Nv[0].w;
            z.x = fmaf(a1, Nv[1].x, z.x); z.y = fmaf(a1, Nv[1].y, z.y);
            z.z = fmaf(a1, Nv[1].z, z.z); z.w = fmaf(a1, Nv[1].w, z.w);
            z.x = fmaf(a2, Nv[2].x, z.x); z.y = fmaf(a2, Nv[2].y, z.y);
            z.z = fmaf(a2, Nv[2].z, z.z); z.w = fmaf(a2, Nv[2].w, z.w);
            z.x = fmaf(a3, Nv[3].x, z.x); z.y = fmaf(a3, Nv[3].y, z.y);
            z.z = fmaf(a3, Nv[3].z, z.z); z.w = fmaf(a3, Nv[3].w, z.w);
            z.x += __shfl_xor(z.x, 16); z.y += __shfl_xor(z.y, 16);
            z.z += __shfl_xor(z.z, 16); z.w += __shfl_xor(z.w, 16);
            z.x += __shfl_xor(z.x, 32); z.y += __shfl_xor(z.y, 32);
            z.z += __shfl_xor(z.z, 32); z.w += __shfl_xor(z.w, 32);
            h4.x = c4.x + z.x; h4.y = c4.y + z.y;
            h4.z = c4.z + z.z; h4.w = c4.w + z.w;
            if (relu_last && it == 2) {
                h4.x = fmaxf(h4.x, 0.f); h4.y = fmaxf(h4.y, 0.f);
                h4.z = fmaxf(h4.z, 0.f); h4.w = fmaxf(h4.w, 0.f);
            }
        }
        return h4;
    };

    // ---- 16x64 tile matmul into one sN tile (24 MFMAs) ----
    auto matmul_tile = [&](float4 f0, float4 f1, float4 f2, float4 f3,
                           float* __restrict__ Nw) {
        bf16x8 A0h, A0l, A1h, A1l;
        split_pack8(f0, f1, A0h, A0l);
        split_pack8(f2, f3, A1h, A1l);
        floatx4 acc[4];
#pragma unroll
        for (int nt = 0; nt < 4; ++nt) {
            acc[nt] = (floatx4){0.f, 0.f, 0.f, 0.f};
            acc[nt] = mfma3(A0h, A0l, wfh[nt][0], wfl[nt][0], acc[nt]);
            acc[nt] = mfma3(A1h, A1l, wfh[nt][1], wfl[nt][1], acc[nt]);
        }
#pragma unroll
        for (int nt = 0; nt < 4; ++nt)
#pragma unroll
            for (int rg = 0; rg < 4; ++rg)
                Nw[(quad * 4 + rg) * 68 + nt * 16 + m16] = acc[nt][rg];
    };

    // ---- issue long-latency gathers early ----
    const long g1 = (long)idx1[b * 16 + m16] * 64;
    const float* p1 = &tab1[g1 + quad * 8];
    float4 e1a = *(const float4*)p1;
    float4 e1b = *(const float4*)(p1 + 4);
    float4 e1c = *(const float4*)(p1 + 32);
    float4 e1d = *(const float4*)(p1 + 36);
    int gidx[4];
#pragma unroll
    for (int q = 0; q < 4; ++q)
        gidx[q] = idx2[b * 256 + (wv * 4 + q) * 16 + m16];

    // ================= layer-1 pre-encode: hid = e1 @ W1c =================
    load_wfrag(w1c_id);
    {
        bf16x8 A0h, A0l, A1h, A1l;
        split_pack8(e1a, e1b, A0h, A0l);
        split_pack8(e1c, e1d, A1h, A1l);
        floatx4 hacc[4];
#pragma unroll
        for (int nt = 0; nt < 4; ++nt) {
            hacc[nt] = (floatx4){0.f, 0.f, 0.f, 0.f};
            hacc[nt] = mfma3(A0h, A0l, wfh[nt][0], wfl[nt][0], hacc[nt]);
            hacc[nt] = mfma3(A1h, A1l, wfh[nt][1], wfl[nt][1], hacc[nt]);
        }
        // D: row = quad*4+reg, col = nt*16+m16. Wave w keeps rows w*4..w*4+3
        // (quad==wv lanes) — exactly its own routing slots. Only sC needed.
        if (quad == wv) {
#pragma unroll
            for (int nt = 0; nt < 4; ++nt)
#pragma unroll
                for (int rg = 0; rg < 4; ++rg)
                    sC[(quad * 4 + rg) * 68 + nt * 16 + m16] = hacc[nt][rg];
        }
    }
    __builtin_amdgcn_wave_barrier();

    // ================= layer-1 main: 4 s-slots per wave =================
    float4 f0, f1, f2, f3;
    {
        const float* p = &tab0[(long)gidx[0] * 64 + quad * 8];
        f0 = *(const float4*)p;        f1 = *(const float4*)(p + 4);
        f2 = *(const float4*)(p + 32); f3 = *(const float4*)(p + 36);
    }
    load_wfrag(w1n_id);
#pragma unroll
    for (int q = 0; q < 4; ++q) {
        const int s = wv * 4 + q;
        matmul_tile(f0, f1, f2, f3, sN[wv]);
        if (q < 3) {  // prefetch next slot's A rows; consumed next iteration
            const float* p = &tab0[(long)gidx[q + 1] * 64 + quad * 8];
            f0 = *(const float4*)p;        f1 = *(const float4*)(p + 4);
            f2 = *(const float4*)(p + 32); f3 = *(const float4*)(p + 36);
        }
        __builtin_amdgcn_wave_barrier();
        float4 c4 = *(const float4*)&sC[s * 68 + 4 * j4];
        float4 h4 = routing_reg(sN[wv], c4, true);
        if (rr == 0)
            *(float4*)&sH[s * 68 + 4 * j4] = h4;   // h1 row s
        __builtin_amdgcn_wave_barrier();           // sN reads done before next matmul
    }

    // ================= layer-0 =================
    __syncthreads();   // the only block barrier: all h1 rows visible
    if (wv == 0) {
        load_wfrag(w0n_id);
        sE0[lane] = v0;
        bf16x8 A0h, A0l, A1h, A1l;
        {
            const float* hp = &sH[m16 * 68];
            split_pack8(*(const float4*)&hp[quad * 8],
                        *(const float4*)&hp[quad * 8 + 4], A0h, A0l);
            split_pack8(*(const float4*)&hp[32 + quad * 8],
                        *(const float4*)&hp[32 + quad * 8 + 4], A1h, A1l);
        }
        floatx4 acc[4];
#pragma unroll
        for (int nt = 0; nt < 4; ++nt) {
            acc[nt] = (floatx4){0.f, 0.f, 0.f, 0.f};
            acc[nt] = mfma3(A0h, A0l, wfh[nt][0], wfl[nt][0], acc[nt]);
            acc[nt] = mfma3(A1h, A1l, wfh[nt][1], wfl[nt][1], acc[nt]);
        }
#pragma unroll
        for (int nt = 0; nt < 4; ++nt)
#pragma unroll
            for (int rg = 0; rg < 4; ++rg)
                sN[0][(quad * 4 + rg) * 68 + nt * 16 + m16] = acc[nt][rg];
        __builtin_amdgcn_wave_barrier();
        float4 c4 = *(const float4*)&sE0[4 * j4];
        float4 h4 = routing_reg(sN[0], c4, false);
        if (rr == 0)
            *(float4*)&out[((long)branch * B + b) * 64 + 4 * j4] = h4;
    }
}

extern "C" void kernel_launch(void* const* d_in, const int* in_sizes, int n_in,
                              void* d_out, int out_size, void* d_ws, size_t ws_size,
                              hipStream_t stream) {
    const float* user_table = (const float*)d_in[0];
    const float* item_table = (const float*)d_in[1];
    const float* W0u = (const float*)d_in[2];
    const float* W0i = (const float*)d_in[3];
    const float* W1u = (const float*)d_in[4];
    const float* W1i = (const float*)d_in[5];
    const int* uidx0 = (const int*)d_in[6];
    const int* uidx1 = (const int*)d_in[7];
    const int* uidx2 = (const int*)d_in[8];
    const int* iidx0 = (const int*)d_in[9];
    const int* iidx1 = (const int*)d_in[10];
    const int* iidx2 = (const int*)d_in[11];
    float* out = (float*)d_out;
    short* pk = (short*)d_ws;   // 4 matrices * 16 frags * 64 lanes * 16B = 64 KB

    const int B = in_sizes[6];  // 2048
    hipLaunchKernelGGL(pack_weights, dim3(4), dim3(256), 0, stream,
                       W0u, W0i, W1u, W1i, pk);
    dim3 grid(B, 2), block(NTH);
    hipLaunchKernelGGL(disenhan_mfma, grid, block, 0, stream,
                       user_table, item_table, (const bf16x8*)pk,
                       uidx0, uidx1, uidx2, iidx0, iidx1, iidx2, out, B);
}